// Round 5
// baseline (1488.791 us; speedup 1.0000x reference)
//
#include <hip/hip_runtime.h>

#define NFFT 16384
#define LSIG 8192
#define NH   1024
#define NTH  512
#define LDSN (NFFT + (NFFT >> 5))   // 16896 floats per plane (pad every 32)

__device__ __forceinline__ int PADI(int i) { return i + (i >> 5); }

struct cplx { float x, y; };
__device__ __forceinline__ cplx cadd(cplx a, cplx b){ return {a.x+b.x, a.y+b.y}; }
__device__ __forceinline__ cplx csub(cplx a, cplx b){ return {a.x-b.x, a.y-b.y}; }
__device__ __forceinline__ cplx cmul(cplx a, cplx b){ return {a.x*b.x - a.y*b.y, a.x*b.y + a.y*b.x}; }

// w32[k] = (cos(2*pi*k/32), sin(2*pi*k/32)), k=0..15
constexpr float W32C[16] = {
  1.0f, 0.9807852804f, 0.9238795325f, 0.8314696123f,
  0.7071067812f, 0.5555702330f, 0.3826834324f, 0.1950903220f,
  0.0f, -0.1950903220f, -0.3826834324f, -0.5555702330f,
  -0.7071067812f, -0.8314696123f, -0.9238795325f, -0.9807852804f };
constexpr float W32S[16] = {
  0.0f, 0.1950903220f, 0.3826834324f, 0.5555702330f,
  0.7071067812f, 0.8314696123f, 0.9238795325f, 0.9807852804f,
  1.0f, 0.9807852804f, 0.9238795325f, 0.8314696123f,
  0.7071067812f, 0.5555702330f, 0.3826834324f, 0.1950903220f };
constexpr int BR3[8] = {0,4,2,6,1,5,3,7};

// One radix-2 pass with COMPILE-TIME span SP -> all indices constant after
// unroll -> arrays stay in registers (rule #20).
template<int N, int SP, bool INV>
__device__ __forceinline__ void fft_pass(cplx* z) {
  #pragma unroll
  for (int b = 0; b < N; b += 2*SP) {
    #pragma unroll
    for (int r = 0; r < SP; ++r) {
      const int kk = r * (16 / SP);        // W_{2SP}^r = W32^{r*16/SP}, SP<=16
      if (!INV) {
        cplx u = z[b+r], v = z[b+r+SP];
        z[b+r] = cadd(u, v);
        cplx d = csub(u, v);
        z[b+r+SP] = cmul(d, cplx{W32C[kk], -W32S[kk]});
      } else {
        cplx t0 = z[b+r], t1 = z[b+r+SP];
        cplx w = cmul(t1, cplx{W32C[kk], W32S[kk]});   // conj twiddle
        z[b+r]    = cadd(t0, w);
        z[b+r+SP] = csub(t0, w);
      }
    }
  }
}

// Forward: natural -> bit-reversed (DIF). Inverse: exact mirror, no 1/N.
template<int N, bool INV>
__device__ __forceinline__ void fft_regs(cplx* z) {
  if constexpr (!INV) {
    if constexpr (N >= 32) fft_pass<N,16,false>(z);
    if constexpr (N >= 16) fft_pass<N, 8,false>(z);
    if constexpr (N >=  8) fft_pass<N, 4,false>(z);
    if constexpr (N >=  4) fft_pass<N, 2,false>(z);
    fft_pass<N,1,false>(z);
  } else {
    fft_pass<N,1,true>(z);
    if constexpr (N >=  4) fft_pass<N, 2,true>(z);
    if constexpr (N >=  8) fft_pass<N, 4,true>(z);
    if constexpr (N >= 16) fft_pass<N, 8,true>(z);
    if constexpr (N >= 32) fft_pass<N,16,true>(z);
  }
}

// LDS radix-8 stage (sub-problem M = 8*S). 4 butterflies/thread at NTH=512.
// __sinf/__cosf (v_sin/v_cos), NOT __sincosf: no address-taken locals.
template<int S, bool INV>
__device__ __forceinline__ void stage8(float* sre, float* sim, int tid) {
  const float ang1 = (INV ? 2.0f : -2.0f) * 3.14159265358979f / (float)(8 * S);
  #pragma unroll
  for (int it = 0; it < (NFFT/8)/NTH; ++it) {
    int bf = tid + it * NTH;                    // 0..2047
    int q = bf / S;
    int r = bf - q * S;
    int base = q * (8 * S) + r;
    float t = ang1 * (float)r;
    cplx w1 = {__cosf(t), __sinf(t)};
    cplx wp[8];
    wp[0] = {1.0f, 0.0f};
    #pragma unroll
    for (int m = 1; m < 8; ++m) wp[m] = cmul(wp[m-1], w1);

    cplx a[8];
    if (!INV) {
      #pragma unroll
      for (int j = 0; j < 8; ++j) { int idx = PADI(base + j*S); a[j] = {sre[idx], sim[idx]}; }
      fft_regs<8,false>(a);                     // a[p] = B[BR3[p]]
      #pragma unroll
      for (int p = 0; p < 8; ++p) {
        const int m = BR3[p];
        cplx o = cmul(a[p], wp[m]);
        int idx = PADI(base + m*S);
        sre[idx] = o.x; sim[idx] = o.y;
      }
    } else {
      #pragma unroll
      for (int p = 0; p < 8; ++p) {
        const int m = BR3[p];
        int idx = PADI(base + m*S);
        cplx v = {sre[idx], sim[idx]};
        a[p] = cmul(v, wp[m]);                  // strip forward twiddle
      }
      fft_regs<8,true>(a);
      #pragma unroll
      for (int j = 0; j < 8; ++j) { int idx = PADI(base + j*S); sre[idx] = a[j].x; sim[idx] = a[j].y; }
    }
  }
}

// One block per h (grid=1024). K FFT once, then loop the 4 batch-pairs.
// amdgpu_waves_per_eu(2,2): LDS (132 KiB) caps at 1 block/CU = 2 waves/SIMD
// anyway; this pins the VGPR budget at 512/2 = 256 so the fused section
// (z[32]=64 + kreg[32]=64 + temps ~ 160 live) does NOT spill. Rounds 1-4 all
// had budget (128/64) < demand -> whole-array scratch demotion -> ~5 GB HBM.
__global__
__attribute__((amdgpu_flat_work_group_size(NTH, NTH)))
__attribute__((amdgpu_waves_per_eu(2, 2)))
void fftconv_kernel(const float* __restrict__ u, const float* __restrict__ kin,
                    float* __restrict__ out) {
  __shared__ float sre[LDSN];
  __shared__ float sim[LDSN];
  const int tid = threadIdx.x;
  const int h = blockIdx.x;

  // ---------------- K row FFT (spectrum kept in registers, pre-scaled) -------
  const float* krow = kin + (size_t)h * LSIG;
  #pragma unroll
  for (int c = 0; c < 4; ++c) {
    int i0 = (c * NTH + tid) * 4;
    float4 v = *reinterpret_cast<const float4*>(krow + i0);
    int p0 = PADI(i0);
    sre[p0+0]=v.x; sre[p0+1]=v.y; sre[p0+2]=v.z; sre[p0+3]=v.w;
    sim[p0+0]=0.f; sim[p0+1]=0.f; sim[p0+2]=0.f; sim[p0+3]=0.f;
    int p1 = PADI(i0 + LSIG);
    sre[p1+0]=0.f; sre[p1+1]=0.f; sre[p1+2]=0.f; sre[p1+3]=0.f;
    sim[p1+0]=0.f; sim[p1+1]=0.f; sim[p1+2]=0.f; sim[p1+3]=0.f;
  }
  __syncthreads();
  stage8<2048,false>(sre, sim, tid); __syncthreads();
  stage8< 256,false>(sre, sim, tid); __syncthreads();
  stage8<  32,false>(sre, sim, tid); __syncthreads();

  cplx kreg[32];
  {
    cplx z[32];
    int p0 = PADI(tid * 32);        // 32 elems contiguous (pad every 32)
    #pragma unroll
    for (int e = 0; e < 32; ++e) z[e] = {sre[p0+e], sim[p0+e]};
    fft_regs<32,false>(z);
    const float scl = 1.0f / (float)NFFT;
    #pragma unroll
    for (int e = 0; e < 32; ++e) kreg[e] = {z[e].x * scl, z[e].y * scl};
  }

  for (int pr = 0; pr < 4; ++pr) {
    __syncthreads();                // LDS safe to overwrite

    const float* u0 = u + ((size_t)(2*pr) * NH + h) * LSIG;
    const float* u1 = u0 + (size_t)NH * LSIG;
    #pragma unroll
    for (int c = 0; c < 4; ++c) {
      int i0 = (c * NTH + tid) * 4;
      float4 a = *reinterpret_cast<const float4*>(u0 + i0);
      float4 b = *reinterpret_cast<const float4*>(u1 + i0);
      int p0 = PADI(i0);
      sre[p0+0]=a.x; sre[p0+1]=a.y; sre[p0+2]=a.z; sre[p0+3]=a.w;
      sim[p0+0]=b.x; sim[p0+1]=b.y; sim[p0+2]=b.z; sim[p0+3]=b.w;
      int p1 = PADI(i0 + LSIG);
      sre[p1+0]=0.f; sre[p1+1]=0.f; sre[p1+2]=0.f; sre[p1+3]=0.f;
      sim[p1+0]=0.f; sim[p1+1]=0.f; sim[p1+2]=0.f; sim[p1+3]=0.f;
    }
    __syncthreads();
    stage8<2048,false>(sre, sim, tid); __syncthreads();
    stage8< 256,false>(sre, sim, tid); __syncthreads();
    stage8<  32,false>(sre, sim, tid); __syncthreads();

    {   // fused: reg-32 FFT, pointwise multiply (scrambled order), reg-32 inv
      cplx z[32];
      int p0 = PADI(tid * 32);
      #pragma unroll
      for (int e = 0; e < 32; ++e) z[e] = {sre[p0+e], sim[p0+e]};
      fft_regs<32,false>(z);
      #pragma unroll
      for (int e = 0; e < 32; ++e) z[e] = cmul(z[e], kreg[e]);
      fft_regs<32,true>(z);
      #pragma unroll
      for (int e = 0; e < 32; ++e) { sre[p0+e] = z[e].x; sim[p0+e] = z[e].y; }
    }
    __syncthreads();
    stage8<  32,true>(sre, sim, tid); __syncthreads();
    stage8< 256,true>(sre, sim, tid); __syncthreads();
    stage8<2048,true>(sre, sim, tid); __syncthreads();

    float* o0 = out + ((size_t)(2*pr) * NH + h) * LSIG;
    float* o1 = o0 + (size_t)NH * LSIG;
    #pragma unroll
    for (int c = 0; c < 4; ++c) {
      int i0 = (c * NTH + tid) * 4;
      int p0 = PADI(i0);
      float4 a = {sre[p0], sre[p0+1], sre[p0+2], sre[p0+3]};
      float4 b = {sim[p0], sim[p0+1], sim[p0+2], sim[p0+3]};
      *reinterpret_cast<float4*>(o0 + i0) = a;
      *reinterpret_cast<float4*>(o1 + i0) = b;
    }
  }
}

extern "C" void kernel_launch(void* const* d_in, const int* in_sizes, int n_in,
                              void* d_out, int out_size, void* d_ws, size_t ws_size,
                              hipStream_t stream) {
  (void)in_sizes; (void)n_in; (void)d_ws; (void)ws_size; (void)out_size;
  const float* u = (const float*)d_in[0];
  const float* k = (const float*)d_in[1];
  float* out = (float*)d_out;
  dim3 grid(NH), block(NTH);
  hipLaunchKernelGGL(fftconv_kernel, grid, block, 0, stream, u, k, out);
}

// Round 6
// 619.243 us; speedup vs baseline: 2.4042x; 2.4042x over previous
//
#include <hip/hip_runtime.h>

#define NFFT 16384
#define LSIG 8192
#define NH   1024
#define NTH  512
#define LDSN (NFFT + (NFFT >> 5))   // 16896 floats per plane (pad every 32)

__device__ __forceinline__ int PADI(int i) { return i + (i >> 5); }

struct cplx { float x, y; };
__device__ __forceinline__ cplx cadd(cplx a, cplx b){ return {a.x+b.x, a.y+b.y}; }
__device__ __forceinline__ cplx csub(cplx a, cplx b){ return {a.x-b.x, a.y-b.y}; }
__device__ __forceinline__ cplx cmul(cplx a, cplx b){ return {a.x*b.x - a.y*b.y, a.x*b.y + a.y*b.x}; }

constexpr float W32C[16] = {
  1.0f, 0.9807852804f, 0.9238795325f, 0.8314696123f,
  0.7071067812f, 0.5555702330f, 0.3826834324f, 0.1950903220f,
  0.0f, -0.1950903220f, -0.3826834324f, -0.5555702330f,
  -0.7071067812f, -0.8314696123f, -0.9238795325f, -0.9807852804f };
constexpr float W32S[16] = {
  0.0f, 0.1950903220f, 0.3826834324f, 0.5555702330f,
  0.7071067812f, 0.8314696123f, 0.9238795325f, 0.9807852804f,
  1.0f, 0.9807852804f, 0.9238795325f, 0.8314696123f,
  0.7071067812f, 0.5555702330f, 0.3826834324f, 0.1950903220f };
constexpr int BR3[8] = {0,4,2,6,1,5,3,7};

// Radix-2 pass, compile-time span SP -> constant indices -> registers.
template<int N, int SP, bool INV>
__device__ __forceinline__ void fft_pass(cplx* z) {
  #pragma unroll
  for (int b = 0; b < N; b += 2*SP) {
    #pragma unroll
    for (int r = 0; r < SP; ++r) {
      const int kk = r * (16 / SP);
      if (!INV) {
        cplx u = z[b+r], v = z[b+r+SP];
        z[b+r] = cadd(u, v);
        cplx d = csub(u, v);
        z[b+r+SP] = cmul(d, cplx{W32C[kk], -W32S[kk]});
      } else {
        cplx t0 = z[b+r], t1 = z[b+r+SP];
        cplx w = cmul(t1, cplx{W32C[kk], W32S[kk]});
        z[b+r]    = cadd(t0, w);
        z[b+r+SP] = csub(t0, w);
      }
    }
  }
}

template<int N, bool INV>
__device__ __forceinline__ void fft_regs(cplx* z) {
  if constexpr (!INV) {
    if constexpr (N >= 32) fft_pass<N,16,false>(z);
    if constexpr (N >= 16) fft_pass<N, 8,false>(z);
    if constexpr (N >=  8) fft_pass<N, 4,false>(z);
    if constexpr (N >=  4) fft_pass<N, 2,false>(z);
    fft_pass<N,1,false>(z);
  } else {
    fft_pass<N,1,true>(z);
    if constexpr (N >=  4) fft_pass<N, 2,true>(z);
    if constexpr (N >=  8) fft_pass<N, 4,true>(z);
    if constexpr (N >= 16) fft_pass<N, 8,true>(z);
    if constexpr (N >= 32) fft_pass<N,16,true>(z);
  }
}

// LDS radix-8 stage (sub-problem M = 8*S). 4 butterflies/thread at NTH=512.
template<int S, bool INV>
__device__ __forceinline__ void stage8(float* sre, float* sim, int tid) {
  const float ang1 = (INV ? 2.0f : -2.0f) * 3.14159265358979f / (float)(8 * S);
  #pragma unroll
  for (int it = 0; it < (NFFT/8)/NTH; ++it) {
    int bf = tid + it * NTH;
    int q = bf / S;
    int r = bf - q * S;
    int base = q * (8 * S) + r;
    float t = ang1 * (float)r;
    cplx w1 = {__cosf(t), __sinf(t)};
    cplx wp[8];
    wp[0] = {1.0f, 0.0f};
    #pragma unroll
    for (int m = 1; m < 8; ++m) wp[m] = cmul(wp[m-1], w1);

    cplx a[8];
    if (!INV) {
      #pragma unroll
      for (int j = 0; j < 8; ++j) { int idx = PADI(base + j*S); a[j] = {sre[idx], sim[idx]}; }
      fft_regs<8,false>(a);
      #pragma unroll
      for (int p = 0; p < 8; ++p) {
        const int m = BR3[p];
        cplx o = cmul(a[p], wp[m]);
        int idx = PADI(base + m*S);
        sre[idx] = o.x; sim[idx] = o.y;
      }
    } else {
      #pragma unroll
      for (int p = 0; p < 8; ++p) {
        const int m = BR3[p];
        int idx = PADI(base + m*S);
        cplx v = {sre[idx], sim[idx]};
        a[p] = cmul(v, wp[m]);
      }
      fft_regs<8,true>(a);
      #pragma unroll
      for (int j = 0; j < 8; ++j) { int idx = PADI(base + j*S); sre[idx] = a[j].x; sim[idx] = a[j].y; }
    }
  }
}

// ---------- kernel 1: K-spectrum precompute into d_ws (scrambled order) -----
__global__ __attribute__((amdgpu_flat_work_group_size(NTH, NTH)))
void kfft_kernel(const float* __restrict__ kin, float2* __restrict__ kh) {
  __shared__ float sre[LDSN];
  __shared__ float sim[LDSN];
  const int tid = threadIdx.x;
  const int h = blockIdx.x;
  const float* krow = kin + (size_t)h * LSIG;
  #pragma unroll
  for (int c = 0; c < 4; ++c) {
    int i0 = (c * NTH + tid) * 4;
    float4 v = *reinterpret_cast<const float4*>(krow + i0);
    int p0 = PADI(i0);
    sre[p0+0]=v.x; sre[p0+1]=v.y; sre[p0+2]=v.z; sre[p0+3]=v.w;
    sim[p0+0]=0.f; sim[p0+1]=0.f; sim[p0+2]=0.f; sim[p0+3]=0.f;
    int p1 = PADI(i0 + LSIG);
    sre[p1+0]=0.f; sre[p1+1]=0.f; sre[p1+2]=0.f; sre[p1+3]=0.f;
    sim[p1+0]=0.f; sim[p1+1]=0.f; sim[p1+2]=0.f; sim[p1+3]=0.f;
  }
  __syncthreads();
  stage8<2048,false>(sre, sim, tid); __syncthreads();
  stage8< 256,false>(sre, sim, tid); __syncthreads();
  stage8<  32,false>(sre, sim, tid); __syncthreads();

  cplx z[32];
  int p0 = PADI(tid * 32);            // 32 elems contiguous (pad every 32)
  #pragma unroll
  for (int e = 0; e < 32; ++e) z[e] = {sre[p0+e], sim[p0+e]};
  fft_regs<32,false>(z);
  const float scl = 1.0f / (float)NFFT;
  float2* row = kh + (size_t)h * NFFT + tid * 32;
  #pragma unroll
  for (int e = 0; e < 32; ++e) row[e] = make_float2(z[e].x * scl, z[e].y * scl);
}

// ---------- kernel 2: conv. grid 4096, h = bid&1023 (same-h 1024 apart ->
// same XCD under 8-way round-robin -> K-hat L2 reuse). No kreg, no pr loop:
// fused live set ~90 regs < the 128 budget the backend always picks. ---------
__global__ __attribute__((amdgpu_flat_work_group_size(NTH, NTH)))
void conv_kernel(const float* __restrict__ u, const float2* __restrict__ kh,
                 float* __restrict__ out) {
  __shared__ float sre[LDSN];
  __shared__ float sim[LDSN];
  const int tid = threadIdx.x;
  const int bid = blockIdx.x;
  const int h  = bid & (NH - 1);
  const int pr = bid >> 10;

  const float* u0 = u + ((size_t)(2*pr) * NH + h) * LSIG;
  const float* u1 = u0 + (size_t)NH * LSIG;
  #pragma unroll
  for (int c = 0; c < 4; ++c) {
    int i0 = (c * NTH + tid) * 4;
    float4 a = *reinterpret_cast<const float4*>(u0 + i0);
    float4 b = *reinterpret_cast<const float4*>(u1 + i0);
    int p0 = PADI(i0);
    sre[p0+0]=a.x; sre[p0+1]=a.y; sre[p0+2]=a.z; sre[p0+3]=a.w;
    sim[p0+0]=b.x; sim[p0+1]=b.y; sim[p0+2]=b.z; sim[p0+3]=b.w;
    int p1 = PADI(i0 + LSIG);
    sre[p1+0]=0.f; sre[p1+1]=0.f; sre[p1+2]=0.f; sre[p1+3]=0.f;
    sim[p1+0]=0.f; sim[p1+1]=0.f; sim[p1+2]=0.f; sim[p1+3]=0.f;
  }
  __syncthreads();
  stage8<2048,false>(sre, sim, tid); __syncthreads();
  stage8< 256,false>(sre, sim, tid); __syncthreads();
  stage8<  32,false>(sre, sim, tid); __syncthreads();

  {   // fused: reg-32 FFT, multiply by K-hat (global, 4 chunks), reg-32 inv
    cplx z[32];
    int p0 = PADI(tid * 32);
    #pragma unroll
    for (int e = 0; e < 32; ++e) z[e] = {sre[p0+e], sim[p0+e]};
    fft_regs<32,false>(z);
    const float2* krow = kh + (size_t)h * NFFT + tid * 32;
    #pragma unroll
    for (int g = 0; g < 4; ++g) {     // 8 cplx per chunk: 4 float4 loads
      float4 k0 = *reinterpret_cast<const float4*>(krow + g*8 + 0);
      float4 k1 = *reinterpret_cast<const float4*>(krow + g*8 + 2);
      float4 k2 = *reinterpret_cast<const float4*>(krow + g*8 + 4);
      float4 k3 = *reinterpret_cast<const float4*>(krow + g*8 + 6);
      z[g*8+0] = cmul(z[g*8+0], cplx{k0.x, k0.y});
      z[g*8+1] = cmul(z[g*8+1], cplx{k0.z, k0.w});
      z[g*8+2] = cmul(z[g*8+2], cplx{k1.x, k1.y});
      z[g*8+3] = cmul(z[g*8+3], cplx{k1.z, k1.w});
      z[g*8+4] = cmul(z[g*8+4], cplx{k2.x, k2.y});
      z[g*8+5] = cmul(z[g*8+5], cplx{k2.z, k2.w});
      z[g*8+6] = cmul(z[g*8+6], cplx{k3.x, k3.y});
      z[g*8+7] = cmul(z[g*8+7], cplx{k3.z, k3.w});
    }
    fft_regs<32,true>(z);
    #pragma unroll
    for (int e = 0; e < 32; ++e) { sre[p0+e] = z[e].x; sim[p0+e] = z[e].y; }
  }
  __syncthreads();
  stage8<  32,true>(sre, sim, tid); __syncthreads();
  stage8< 256,true>(sre, sim, tid); __syncthreads();
  stage8<2048,true>(sre, sim, tid); __syncthreads();

  float* o0 = out + ((size_t)(2*pr) * NH + h) * LSIG;
  float* o1 = o0 + (size_t)NH * LSIG;
  #pragma unroll
  for (int c = 0; c < 4; ++c) {
    int i0 = (c * NTH + tid) * 4;
    int p0 = PADI(i0);
    float4 a = {sre[p0], sre[p0+1], sre[p0+2], sre[p0+3]};
    float4 b = {sim[p0], sim[p0+1], sim[p0+2], sim[p0+3]};
    *reinterpret_cast<float4*>(o0 + i0) = a;
    *reinterpret_cast<float4*>(o1 + i0) = b;
  }
}

// ---------- fallback (round-3 monolithic, known-good) if ws too small -------
__global__ __attribute__((amdgpu_flat_work_group_size(NTH, NTH)))
void fftconv_fallback(const float* __restrict__ u, const float* __restrict__ kin,
                      float* __restrict__ out) {
  __shared__ float sre[LDSN];
  __shared__ float sim[LDSN];
  const int tid = threadIdx.x;
  const int bid = blockIdx.x;
  const int h  = bid & (NH - 1);
  const int pr = bid >> 10;

  const float* krow = kin + (size_t)h * LSIG;
  #pragma unroll
  for (int c = 0; c < 4; ++c) {
    int i0 = (c * NTH + tid) * 4;
    float4 v = *reinterpret_cast<const float4*>(krow + i0);
    int p0 = PADI(i0);
    sre[p0+0]=v.x; sre[p0+1]=v.y; sre[p0+2]=v.z; sre[p0+3]=v.w;
    sim[p0+0]=0.f; sim[p0+1]=0.f; sim[p0+2]=0.f; sim[p0+3]=0.f;
    int p1 = PADI(i0 + LSIG);
    sre[p1+0]=0.f; sre[p1+1]=0.f; sre[p1+2]=0.f; sre[p1+3]=0.f;
    sim[p1+0]=0.f; sim[p1+1]=0.f; sim[p1+2]=0.f; sim[p1+3]=0.f;
  }
  __syncthreads();
  stage8<2048,false>(sre, sim, tid); __syncthreads();
  stage8< 256,false>(sre, sim, tid); __syncthreads();
  stage8<  32,false>(sre, sim, tid); __syncthreads();

  cplx kreg[32];
  {
    cplx z[32];
    int p0 = PADI(tid * 32);
    #pragma unroll
    for (int e = 0; e < 32; ++e) z[e] = {sre[p0+e], sim[p0+e]};
    fft_regs<32,false>(z);
    const float scl = 1.0f / (float)NFFT;
    #pragma unroll
    for (int e = 0; e < 32; ++e) kreg[e] = {z[e].x * scl, z[e].y * scl};
  }
  __syncthreads();

  const float* u0 = u + ((size_t)(2*pr) * NH + h) * LSIG;
  const float* u1 = u0 + (size_t)NH * LSIG;
  #pragma unroll
  for (int c = 0; c < 4; ++c) {
    int i0 = (c * NTH + tid) * 4;
    float4 a = *reinterpret_cast<const float4*>(u0 + i0);
    float4 b = *reinterpret_cast<const float4*>(u1 + i0);
    int p0 = PADI(i0);
    sre[p0+0]=a.x; sre[p0+1]=a.y; sre[p0+2]=a.z; sre[p0+3]=a.w;
    sim[p0+0]=b.x; sim[p0+1]=b.y; sim[p0+2]=b.z; sim[p0+3]=b.w;
    int p1 = PADI(i0 + LSIG);
    sre[p1+0]=0.f; sre[p1+1]=0.f; sre[p1+2]=0.f; sre[p1+3]=0.f;
    sim[p1+0]=0.f; sim[p1+1]=0.f; sim[p1+2]=0.f; sim[p1+3]=0.f;
  }
  __syncthreads();
  stage8<2048,false>(sre, sim, tid); __syncthreads();
  stage8< 256,false>(sre, sim, tid); __syncthreads();
  stage8<  32,false>(sre, sim, tid); __syncthreads();

  {
    cplx z[32];
    int p0 = PADI(tid * 32);
    #pragma unroll
    for (int e = 0; e < 32; ++e) z[e] = {sre[p0+e], sim[p0+e]};
    fft_regs<32,false>(z);
    #pragma unroll
    for (int e = 0; e < 32; ++e) z[e] = cmul(z[e], kreg[e]);
    fft_regs<32,true>(z);
    #pragma unroll
    for (int e = 0; e < 32; ++e) { sre[p0+e] = z[e].x; sim[p0+e] = z[e].y; }
  }
  __syncthreads();
  stage8<  32,true>(sre, sim, tid); __syncthreads();
  stage8< 256,true>(sre, sim, tid); __syncthreads();
  stage8<2048,true>(sre, sim, tid); __syncthreads();

  float* o0 = out + ((size_t)(2*pr) * NH + h) * LSIG;
  float* o1 = o0 + (size_t)NH * LSIG;
  #pragma unroll
  for (int c = 0; c < 4; ++c) {
    int i0 = (c * NTH + tid) * 4;
    int p0 = PADI(i0);
    float4 a = {sre[p0], sre[p0+1], sre[p0+2], sre[p0+3]};
    float4 b = {sim[p0], sim[p0+1], sim[p0+2], sim[p0+3]};
    *reinterpret_cast<float4*>(o0 + i0) = a;
    *reinterpret_cast<float4*>(o1 + i0) = b;
  }
}

extern "C" void kernel_launch(void* const* d_in, const int* in_sizes, int n_in,
                              void* d_out, int out_size, void* d_ws, size_t ws_size,
                              hipStream_t stream) {
  (void)in_sizes; (void)n_in; (void)out_size;
  const float* u = (const float*)d_in[0];
  const float* k = (const float*)d_in[1];
  float* out = (float*)d_out;
  const size_t need = (size_t)NH * NFFT * sizeof(float2);   // 128 MiB
  if (ws_size >= need) {
    hipLaunchKernelGGL(kfft_kernel, dim3(NH),   dim3(NTH), 0, stream, k, (float2*)d_ws);
    hipLaunchKernelGGL(conv_kernel, dim3(4096), dim3(NTH), 0, stream, u, (const float2*)d_ws, out);
  } else {
    hipLaunchKernelGGL(fftconv_fallback, dim3(4096), dim3(NTH), 0, stream, u, k, out);
  }
}

// Round 7
// 520.141 us; speedup vs baseline: 2.8623x; 1.1905x over previous
//
#include <hip/hip_runtime.h>

#define NFFT 16384
#define LSIG 8192
#define NH   1024
#define NTH  512
#define LDSN (NFFT + (NFFT >> 5))   // pad every 32 floats

__device__ __forceinline__ int PADI(int i) { return i + (i >> 5); }

struct cplx { float x, y; };
__device__ __forceinline__ cplx cadd(cplx a, cplx b){ return {a.x+b.x, a.y+b.y}; }
__device__ __forceinline__ cplx csub(cplx a, cplx b){ return {a.x-b.x, a.y-b.y}; }
__device__ __forceinline__ cplx cmul(cplx a, cplx b){ return {a.x*b.x - a.y*b.y, a.x*b.y + a.y*b.x}; }

constexpr float W32C[16] = {
  1.0f, 0.9807852804f, 0.9238795325f, 0.8314696123f,
  0.7071067812f, 0.5555702330f, 0.3826834324f, 0.1950903220f,
  0.0f, -0.1950903220f, -0.3826834324f, -0.5555702330f,
  -0.7071067812f, -0.8314696123f, -0.9238795325f, -0.9807852804f };
constexpr float W32S[16] = {
  0.0f, 0.1950903220f, 0.3826834324f, 0.5555702330f,
  0.7071067812f, 0.8314696123f, 0.9238795325f, 0.9807852804f,
  1.0f, 0.9807852804f, 0.9238795325f, 0.8314696123f,
  0.7071067812f, 0.5555702330f, 0.3826834324f, 0.1950903220f };
constexpr int BR3[8] = {0,4,2,6,1,5,3,7};

// Radix-2 pass, compile-time span SP -> constant indices -> registers.
template<int N, int SP, bool INV>
__device__ __forceinline__ void fft_pass(cplx* z) {
  #pragma unroll
  for (int b = 0; b < N; b += 2*SP) {
    #pragma unroll
    for (int r = 0; r < SP; ++r) {
      const int kk = r * (16 / SP);
      if (!INV) {
        cplx u = z[b+r], v = z[b+r+SP];
        z[b+r] = cadd(u, v);
        cplx d = csub(u, v);
        z[b+r+SP] = cmul(d, cplx{W32C[kk], -W32S[kk]});
      } else {
        cplx t0 = z[b+r], t1 = z[b+r+SP];
        cplx w = cmul(t1, cplx{W32C[kk], W32S[kk]});
        z[b+r]    = cadd(t0, w);
        z[b+r+SP] = csub(t0, w);
      }
    }
  }
}

template<int N, bool INV>
__device__ __forceinline__ void fft_regs(cplx* z) {
  if constexpr (!INV) {
    if constexpr (N >= 32) fft_pass<N,16,false>(z);
    if constexpr (N >= 16) fft_pass<N, 8,false>(z);
    if constexpr (N >=  8) fft_pass<N, 4,false>(z);
    if constexpr (N >=  4) fft_pass<N, 2,false>(z);
    fft_pass<N,1,false>(z);
  } else {
    fft_pass<N,1,true>(z);
    if constexpr (N >=  4) fft_pass<N, 2,true>(z);
    if constexpr (N >=  8) fft_pass<N, 4,true>(z);
    if constexpr (N >= 16) fft_pass<N, 8,true>(z);
    if constexpr (N >= 32) fft_pass<N,16,true>(z);
  }
}

// LDS radix-8 stage for S >= 32 (measured conflict-free in rounds 1-6).
template<int S, bool INV>
__device__ __forceinline__ void stage8(float* sre, float* sim, int tid) {
  const float ang1 = (INV ? 2.0f : -2.0f) * 3.14159265358979f / (float)(8 * S);
  #pragma unroll
  for (int it = 0; it < (NFFT/8)/NTH; ++it) {
    int bf = tid + it * NTH;
    int q = bf / S;
    int r = bf - q * S;
    int base = q * (8 * S) + r;
    float t = ang1 * (float)r;
    cplx w1 = {__cosf(t), __sinf(t)};
    cplx wp[8];
    wp[0] = {1.0f, 0.0f};
    #pragma unroll
    for (int m = 1; m < 8; ++m) wp[m] = cmul(wp[m-1], w1);

    cplx a[8];
    if (!INV) {
      #pragma unroll
      for (int j = 0; j < 8; ++j) { int idx = PADI(base + j*S); a[j] = {sre[idx], sim[idx]}; }
      fft_regs<8,false>(a);
      #pragma unroll
      for (int p = 0; p < 8; ++p) {
        const int m = BR3[p];
        cplx o = cmul(a[p], wp[m]);
        int idx = PADI(base + m*S);
        sre[idx] = o.x; sim[idx] = o.y;
      }
    } else {
      #pragma unroll
      for (int p = 0; p < 8; ++p) {
        const int m = BR3[p];
        int idx = PADI(base + m*S);
        cplx v = {sre[idx], sim[idx]};
        a[p] = cmul(v, wp[m]);
      }
      fft_regs<8,true>(a);
      #pragma unroll
      for (int j = 0; j < 8; ++j) { int idx = PADI(base + j*S); sre[idx] = a[j].x; sim[idx] = a[j].y; }
    }
  }
}

// LDS radix-8 stage, S = 4 (M = 32). Thread t owns sub-problem q = t:
// addresses t*32 + r + 4m -> after pad, bank = (t + r + 4m) mod 32 ->
// exactly 2 lanes/bank = free (m136).
template<bool INV>
__device__ __forceinline__ void stage8_s4(float* sre, float* sim, int tid) {
  const float ang1 = (INV ? 2.0f : -2.0f) * 3.14159265358979f / 32.0f;
  #pragma unroll
  for (int r = 0; r < 4; ++r) {
    int base = tid * 32 + r;
    float t = ang1 * (float)r;
    cplx w1 = {__cosf(t), __sinf(t)};
    cplx wp[8];
    wp[0] = {1.0f, 0.0f};
    #pragma unroll
    for (int m = 1; m < 8; ++m) wp[m] = cmul(wp[m-1], w1);

    cplx a[8];
    if (!INV) {
      #pragma unroll
      for (int j = 0; j < 8; ++j) { int idx = PADI(base + j*4); a[j] = {sre[idx], sim[idx]}; }
      fft_regs<8,false>(a);
      #pragma unroll
      for (int p = 0; p < 8; ++p) {
        const int m = BR3[p];
        cplx o = cmul(a[p], wp[m]);
        int idx = PADI(base + m*4);
        sre[idx] = o.x; sim[idx] = o.y;
      }
    } else {
      #pragma unroll
      for (int p = 0; p < 8; ++p) {
        const int m = BR3[p];
        int idx = PADI(base + m*4);
        cplx v = {sre[idx], sim[idx]};
        a[p] = cmul(v, wp[m]);
      }
      fft_regs<8,true>(a);
      #pragma unroll
      for (int j = 0; j < 8; ++j) { int idx = PADI(base + j*4); sre[idx] = a[j].x; sim[idx] = a[j].y; }
    }
  }
}

// ---------- kernel 1: K-spectrum precompute into d_ws (scrambled order) -----
__global__ __launch_bounds__(NTH)
void kfft_kernel(const float* __restrict__ kin, float2* __restrict__ kh) {
  __shared__ float sre[LDSN];
  __shared__ float sim[LDSN];
  const int tid = threadIdx.x;
  const int h = blockIdx.x;
  const float* krow = kin + (size_t)h * LSIG;
  #pragma unroll
  for (int c = 0; c < 4; ++c) {
    int i0 = (c * NTH + tid) * 4;
    float4 v = *reinterpret_cast<const float4*>(krow + i0);
    int p0 = PADI(i0);
    sre[p0+0]=v.x; sre[p0+1]=v.y; sre[p0+2]=v.z; sre[p0+3]=v.w;
    sim[p0+0]=0.f; sim[p0+1]=0.f; sim[p0+2]=0.f; sim[p0+3]=0.f;
    int p1 = PADI(i0 + LSIG);
    sre[p1+0]=0.f; sre[p1+1]=0.f; sre[p1+2]=0.f; sre[p1+3]=0.f;
    sim[p1+0]=0.f; sim[p1+1]=0.f; sim[p1+2]=0.f; sim[p1+3]=0.f;
  }
  __syncthreads();
  stage8<2048,false>(sre, sim, tid); __syncthreads();
  stage8< 256,false>(sre, sim, tid); __syncthreads();
  stage8<  32,false>(sre, sim, tid); __syncthreads();
  stage8_s4<false>(sre, sim, tid);   __syncthreads();

  const float scl = 1.0f / (float)NFFT;
  float2* row = kh + (size_t)h * NFFT;
  #pragma unroll
  for (int s = 0; s < 8; ++s) {       // quad m = tid + 512*s
    int m = tid + NTH * s;
    int i0 = 4 * m;
    int p = PADI(i0);                 // 4 floats contiguous (no pad crossing)
    cplx z[4] = { {sre[p+0], sim[p+0]}, {sre[p+1], sim[p+1]},
                  {sre[p+2], sim[p+2]}, {sre[p+3], sim[p+3]} };
    fft_regs<4,false>(z);
    #pragma unroll
    for (int e = 0; e < 4; ++e) row[i0+e] = make_float2(z[e].x*scl, z[e].y*scl);
  }
}

// ---------- kernel 2: conv. grid 4096, h = bid>>2 -> the 4 same-h blocks are
// temporally adjacent -> K-hat row reused from L3/L2 instead of 4x HBM. ------
__global__ __launch_bounds__(NTH)
void conv_kernel(const float* __restrict__ u, const float2* __restrict__ kh,
                 float* __restrict__ out) {
  __shared__ float sre[LDSN];
  __shared__ float sim[LDSN];
  const int tid = threadIdx.x;
  const int bid = blockIdx.x;
  const int h  = bid >> 2;
  const int pr = bid & 3;

  const float* u0 = u + ((size_t)(2*pr) * NH + h) * LSIG;
  const float* u1 = u0 + (size_t)NH * LSIG;
  #pragma unroll
  for (int c = 0; c < 4; ++c) {
    int i0 = (c * NTH + tid) * 4;
    float4 a = *reinterpret_cast<const float4*>(u0 + i0);
    float4 b = *reinterpret_cast<const float4*>(u1 + i0);
    int p0 = PADI(i0);
    sre[p0+0]=a.x; sre[p0+1]=a.y; sre[p0+2]=a.z; sre[p0+3]=a.w;
    sim[p0+0]=b.x; sim[p0+1]=b.y; sim[p0+2]=b.z; sim[p0+3]=b.w;
    int p1 = PADI(i0 + LSIG);
    sre[p1+0]=0.f; sre[p1+1]=0.f; sre[p1+2]=0.f; sre[p1+3]=0.f;
    sim[p1+0]=0.f; sim[p1+1]=0.f; sim[p1+2]=0.f; sim[p1+3]=0.f;
  }
  __syncthreads();
  stage8<2048,false>(sre, sim, tid); __syncthreads();
  stage8< 256,false>(sre, sim, tid); __syncthreads();
  stage8<  32,false>(sre, sim, tid); __syncthreads();
  stage8_s4<false>(sre, sim, tid);   __syncthreads();

  // fused per-quad: DFT4 -> multiply K-hat -> inverse DFT4. Live ~20 regs.
  {
    const float2* krow = kh + (size_t)h * NFFT;
    #pragma unroll
    for (int s = 0; s < 8; ++s) {     // quad m = tid + 512*s (coalesced kh)
      int m = tid + NTH * s;
      int i0 = 4 * m;
      int p = PADI(i0);
      cplx z[4] = { {sre[p+0], sim[p+0]}, {sre[p+1], sim[p+1]},
                    {sre[p+2], sim[p+2]}, {sre[p+3], sim[p+3]} };
      fft_regs<4,false>(z);
      float4 k0 = *reinterpret_cast<const float4*>(krow + i0 + 0);
      float4 k1 = *reinterpret_cast<const float4*>(krow + i0 + 2);
      z[0] = cmul(z[0], cplx{k0.x, k0.y});
      z[1] = cmul(z[1], cplx{k0.z, k0.w});
      z[2] = cmul(z[2], cplx{k1.x, k1.y});
      z[3] = cmul(z[3], cplx{k1.z, k1.w});
      fft_regs<4,true>(z);
      #pragma unroll
      for (int e = 0; e < 4; ++e) { sre[p+e] = z[e].x; sim[p+e] = z[e].y; }
    }
  }
  __syncthreads();
  stage8_s4<true>(sre, sim, tid);   __syncthreads();
  stage8<  32,true>(sre, sim, tid); __syncthreads();
  stage8< 256,true>(sre, sim, tid); __syncthreads();
  stage8<2048,true>(sre, sim, tid); __syncthreads();

  float* o0 = out + ((size_t)(2*pr) * NH + h) * LSIG;
  float* o1 = o0 + (size_t)NH * LSIG;
  #pragma unroll
  for (int c = 0; c < 4; ++c) {
    int i0 = (c * NTH + tid) * 4;
    int p0 = PADI(i0);
    float4 a = {sre[p0], sre[p0+1], sre[p0+2], sre[p0+3]};
    float4 b = {sim[p0], sim[p0+1], sim[p0+2], sim[p0+3]};
    *reinterpret_cast<float4*>(o0 + i0) = a;
    *reinterpret_cast<float4*>(o1 + i0) = b;
  }
}

// ---------- fallback (monolithic, known-good) if ws too small ---------------
__global__ __launch_bounds__(NTH)
void fftconv_fallback(const float* __restrict__ u, const float* __restrict__ kin,
                      float* __restrict__ out) {
  __shared__ float sre[LDSN];
  __shared__ float sim[LDSN];
  const int tid = threadIdx.x;
  const int bid = blockIdx.x;
  const int h  = bid >> 2;
  const int pr = bid & 3;

  const float* krow = kin + (size_t)h * LSIG;
  #pragma unroll
  for (int c = 0; c < 4; ++c) {
    int i0 = (c * NTH + tid) * 4;
    float4 v = *reinterpret_cast<const float4*>(krow + i0);
    int p0 = PADI(i0);
    sre[p0+0]=v.x; sre[p0+1]=v.y; sre[p0+2]=v.z; sre[p0+3]=v.w;
    sim[p0+0]=0.f; sim[p0+1]=0.f; sim[p0+2]=0.f; sim[p0+3]=0.f;
    int p1 = PADI(i0 + LSIG);
    sre[p1+0]=0.f; sre[p1+1]=0.f; sre[p1+2]=0.f; sre[p1+3]=0.f;
    sim[p1+0]=0.f; sim[p1+1]=0.f; sim[p1+2]=0.f; sim[p1+3]=0.f;
  }
  __syncthreads();
  stage8<2048,false>(sre, sim, tid); __syncthreads();
  stage8< 256,false>(sre, sim, tid); __syncthreads();
  stage8<  32,false>(sre, sim, tid); __syncthreads();
  stage8_s4<false>(sre, sim, tid);   __syncthreads();

  cplx kq[4][4];     // this thread's 4 quads of K-hat (m = tid + 512*s, s<4)
  cplx kq2[4][4];    // s = 4..7
  const float scl = 1.0f / (float)NFFT;
  #pragma unroll
  for (int s = 0; s < 8; ++s) {
    int m = tid + NTH * s;
    int p = PADI(4 * m);
    cplx z[4] = { {sre[p+0], sim[p+0]}, {sre[p+1], sim[p+1]},
                  {sre[p+2], sim[p+2]}, {sre[p+3], sim[p+3]} };
    fft_regs<4,false>(z);
    #pragma unroll
    for (int e = 0; e < 4; ++e) {
      cplx v = {z[e].x*scl, z[e].y*scl};
      if (s < 4) kq[s][e] = v; else kq2[s-4][e] = v;
    }
  }
  __syncthreads();

  const float* u0 = u + ((size_t)(2*pr) * NH + h) * LSIG;
  const float* u1 = u0 + (size_t)NH * LSIG;
  #pragma unroll
  for (int c = 0; c < 4; ++c) {
    int i0 = (c * NTH + tid) * 4;
    float4 a = *reinterpret_cast<const float4*>(u0 + i0);
    float4 b = *reinterpret_cast<const float4*>(u1 + i0);
    int p0 = PADI(i0);
    sre[p0+0]=a.x; sre[p0+1]=a.y; sre[p0+2]=a.z; sre[p0+3]=a.w;
    sim[p0+0]=b.x; sim[p0+1]=b.y; sim[p0+2]=b.z; sim[p0+3]=b.w;
    int p1 = PADI(i0 + LSIG);
    sre[p1+0]=0.f; sre[p1+1]=0.f; sre[p1+2]=0.f; sre[p1+3]=0.f;
    sim[p1+0]=0.f; sim[p1+1]=0.f; sim[p1+2]=0.f; sim[p1+3]=0.f;
  }
  __syncthreads();
  stage8<2048,false>(sre, sim, tid); __syncthreads();
  stage8< 256,false>(sre, sim, tid); __syncthreads();
  stage8<  32,false>(sre, sim, tid); __syncthreads();
  stage8_s4<false>(sre, sim, tid);   __syncthreads();

  #pragma unroll
  for (int s = 0; s < 8; ++s) {
    int m = tid + NTH * s;
    int p = PADI(4 * m);
    cplx z[4] = { {sre[p+0], sim[p+0]}, {sre[p+1], sim[p+1]},
                  {sre[p+2], sim[p+2]}, {sre[p+3], sim[p+3]} };
    fft_regs<4,false>(z);
    #pragma unroll
    for (int e = 0; e < 4; ++e) z[e] = cmul(z[e], (s<4) ? kq[s][e] : kq2[s-4][e]);
    fft_regs<4,true>(z);
    #pragma unroll
    for (int e = 0; e < 4; ++e) { sre[p+e] = z[e].x; sim[p+e] = z[e].y; }
  }
  __syncthreads();
  stage8_s4<true>(sre, sim, tid);   __syncthreads();
  stage8<  32,true>(sre, sim, tid); __syncthreads();
  stage8< 256,true>(sre, sim, tid); __syncthreads();
  stage8<2048,true>(sre, sim, tid); __syncthreads();

  float* o0 = out + ((size_t)(2*pr) * NH + h) * LSIG;
  float* o1 = o0 + (size_t)NH * LSIG;
  #pragma unroll
  for (int c = 0; c < 4; ++c) {
    int i0 = (c * NTH + tid) * 4;
    int p0 = PADI(i0);
    float4 a = {sre[p0], sre[p0+1], sre[p0+2], sre[p0+3]};
    float4 b = {sim[p0], sim[p0+1], sim[p0+2], sim[p0+3]};
    *reinterpret_cast<float4*>(o0 + i0) = a;
    *reinterpret_cast<float4*>(o1 + i0) = b;
  }
}

extern "C" void kernel_launch(void* const* d_in, const int* in_sizes, int n_in,
                              void* d_out, int out_size, void* d_ws, size_t ws_size,
                              hipStream_t stream) {
  (void)in_sizes; (void)n_in; (void)out_size;
  const float* u = (const float*)d_in[0];
  const float* k = (const float*)d_in[1];
  float* out = (float*)d_out;
  const size_t need = (size_t)NH * NFFT * sizeof(float2);   // 128 MiB
  if (ws_size >= need) {
    hipLaunchKernelGGL(kfft_kernel, dim3(NH),   dim3(NTH), 0, stream, k, (float2*)d_ws);
    hipLaunchKernelGGL(conv_kernel, dim3(4096), dim3(NTH), 0, stream, u, (const float2*)d_ws, out);
  } else {
    hipLaunchKernelGGL(fftconv_fallback, dim3(4096), dim3(NTH), 0, stream, u, k, out);
  }
}